// Round 12
// baseline (264.021 us; speedup 1.0000x reference)
//
#include <hip/hip_runtime.h>

#define L 256
#define BATCH 512
#define CIN 32
#define HIDN 128
#define OUTN 512

typedef _Float16 f16x8 __attribute__((ext_vector_type(8)));
typedef float f32x4 __attribute__((ext_vector_type(4)));

#define MFMA16(a, b, c) __builtin_amdgcn_mfma_f32_16x16x32_f16(a, b, c, 0, 0, 0)

static __device__ __forceinline__ unsigned short f16b(_Float16 h) {
    unsigned short u; __builtin_memcpy(&u, &h, 2); return u;
}

// ws layout (bytes):
//   Wh   @ 0      (32768)  fp16 hi of W_hh [j][k]
//   Wl   @ 32768  (32768)  fp16 lo residual (W to 22 bits; systematic error)
//   Wch  @ 65536  (8192)   fp16 hi of Wc = W_ih@W_in [j][c]
//   Wcl  @ 73728  (8192)
//   bpre @ 81920  (512)    fp32 b_ih + b_hh + W_ih@b_in
//   hs   @ 98304  (33554432) fp16 hs[t*65536 + b*128 + j]

__global__ __launch_bounds__(256) void prep_kernel(
    const float* __restrict__ W_in, const float* __restrict__ b_in,
    const float* __restrict__ W_ih, const float* __restrict__ b_ih,
    const float* __restrict__ b_hh, const float* __restrict__ Whh,
    unsigned short* __restrict__ Wh, unsigned short* __restrict__ Wl,
    unsigned short* __restrict__ Wch, unsigned short* __restrict__ Wcl,
    float* __restrict__ bpre)
{
    const int tid = threadIdx.x;
    __shared__ float win[64 * CIN];
    for (int i = tid; i < 64 * CIN; i += 256) win[i] = W_in[i];
    __syncthreads();
    if (tid < 128) {
        const int j = tid;
        float acc[CIN];
#pragma unroll
        for (int c = 0; c < CIN; ++c) acc[c] = 0.f;
        float bs = b_ih[j] + b_hh[j];
        for (int m = 0; m < 64; ++m) {
            float w = W_ih[j * 64 + m];
            bs += w * b_in[m];
#pragma unroll
            for (int c = 0; c < CIN; ++c) acc[c] += w * win[m * CIN + c];
        }
        bpre[j] = bs;
#pragma unroll
        for (int c = 0; c < CIN; ++c) {
            _Float16 h = (_Float16)acc[c];
            _Float16 l = (_Float16)(acc[c] - (float)h);
            Wch[j * CIN + c] = f16b(h);
            Wcl[j * CIN + c] = f16b(l);
        }
    } else {
        const int j = tid - 128;
        for (int k = 0; k < HIDN; k += 4) {
            float4 v = *(const float4*)(Whh + j * HIDN + k);
            float vv[4] = {v.x, v.y, v.z, v.w};
#pragma unroll
            for (int u = 0; u < 4; ++u) {
                _Float16 h = (_Float16)vv[u];
                _Float16 l = (_Float16)(vv[u] - (float)h);
                Wh[j * HIDN + k + u] = f16b(h);
                Wl[j * HIDN + k + u] = f16b(l);
            }
        }
    }
}

// MFMA RNN, fp16 2-term split. 32 blocks (16 batch rows) x 512 thr (8 waves).
// R11 changes vs R10 (chain-shortening; R10 step = 1085 cyc, floor ~400):
//  - 4 independent MFMA chains <=3 deep; the x-MFMAs (register operands)
//    issue immediately post-barrier, covering h ds_read latency.
//  - x B-frag prefetched 1 step ahead in a register (read early, so the
//    pre-barrier lgkm drain never exposes its latency).
//  - hs stores register-buffered per 16-step chunk (t-loop = 16 outer x
//    16 fully-unrolled inner -> constant reg indexing), flushed as one
//    16-store burst off the critical path.
__global__ __launch_bounds__(512, 1) void rnn_kernel(
    const float* __restrict__ x, const float* __restrict__ h0,
    const unsigned short* __restrict__ Wh, const unsigned short* __restrict__ Wl,
    const unsigned short* __restrict__ Wch, const unsigned short* __restrict__ Wcl,
    const float* __restrict__ bpre, unsigned short* __restrict__ hs)
{
    const int tid = threadIdx.x;
    const int bb = blockIdx.x;
    const int lane = tid & 63;
    const int w = tid >> 6;       // wave 0..7
    const int n = lane & 15;      // batch col / A row
    const int q = lane >> 4;      // quad

    __shared__ unsigned short hbuf[2][16][HIDN];     // 8 KB, granule swizzle ^(n&7)
    __shared__ unsigned short xc[2][16][16][CIN];    // 32 KB, [chunk][t&15][n][c]

    const f32x4 ZERO4 = {0.f, 0.f, 0.f, 0.f};

    // A-frags: A[m=lane&15][k=q*8+i]; rows = j = w*16 + n
    f16x8 Ah[4], Al[4], Axh, Axl;
    const int jr = w * 16 + n;
#pragma unroll
    for (int kc = 0; kc < 4; ++kc) {
        Ah[kc] = *(const f16x8*)(Wh + jr * HIDN + kc * 32 + q * 8);
        Al[kc] = *(const f16x8*)(Wl + jr * HIDN + kc * 32 + q * 8);
    }
    Axh = *(const f16x8*)(Wch + jr * CIN + q * 8);
    Axl = *(const f16x8*)(Wcl + jr * CIN + q * 8);
    float4 bv = *(const float4*)(bpre + w * 16 + q * 4);
    f32x4 bp = {bv.x, bv.y, bv.z, bv.w};

    // ---- h0 -> fp16 plane, dbuf 0 (first 256 threads) ----
    if (tid < 256) {
        const int ni = tid >> 4, gi = tid & 15;
        const float4* src = (const float4*)(h0 + ((size_t)bb * 16 + ni) * HIDN + gi * 8);
        float4 a = src[0], b4 = src[1];
        float vv[8] = {a.x, a.y, a.z, a.w, b4.x, b4.y, b4.z, b4.w};
        unsigned short o[8];
#pragma unroll
        for (int i = 0; i < 8; ++i) o[i] = f16b((_Float16)vv[i]);
        *(uint4*)&hbuf[0][ni][(gi ^ (ni & 7)) * 8] = *(uint4*)o;
    }

    // ---- x chunk staging over 512 threads: i=tid+r*512 -> (nn,cc,tq) ----
    float4 xr[4];
    auto issue_chunk = [&](int ci) {
#pragma unroll
        for (int r = 0; r < 4; ++r) {
            int i = tid + r * 512;
            int nn = i >> 7, cc = (i >> 2) & 31, tq = i & 3;
            xr[r] = *(const float4*)(x + (((size_t)bb * 16 + nn) * CIN + cc) * L + ci * 16 + tq * 4);
        }
    };
    auto write_chunk = [&](int buf) {
#pragma unroll
        for (int r = 0; r < 4; ++r) {
            int i = tid + r * 512;
            int nn = i >> 7, cc = (i >> 2) & 31, tq = i & 3;
            float vv[4] = {xr[r].x, xr[r].y, xr[r].z, xr[r].w};
#pragma unroll
            for (int k = 0; k < 4; ++k)
                xc[buf][tq * 4 + k][nn][cc] = f16b((_Float16)vv[k]);
        }
    };

    issue_chunk(0);
    write_chunk(0);
    issue_chunk(1);
    __syncthreads();

    unsigned short* hsp = hs + ((size_t)bb * 16 + n) * HIDN + w * 16 + q * 4;

    f16x8 xB, xBn;
    uint2 hsbuf[16];

    for (int c16 = 0; c16 < 16; ++c16) {
        const int cb = c16 & 1;
#pragma unroll
        for (int tt = 0; tt < 16; ++tt) {       // fully unrolled: tt is constant
            const int p = tt & 1;               // 16*c16 is even

            // post-barrier reads first
            f16x8 Bh[4];
#pragma unroll
            for (int kc = 0; kc < 4; ++kc)
                Bh[kc] = *(const f16x8*)&hbuf[p][n][((4 * kc + q) ^ (n & 7)) * 8];
            if (tt == 0) xB = *(const f16x8*)&xc[cb][0][n][q * 8];
            if (tt < 15) xBn = *(const f16x8*)&xc[cb][tt + 1][n][q * 8];  // prefetch

            // 4 chains <=3 deep; x-chains issue immediately (register operand)
            f32x4 c1 = MFMA16(Axh, xB, ZERO4);
            f32x4 c2 = MFMA16(Axl, xB, ZERO4);
            c1 = MFMA16(Ah[0], Bh[0], c1);
            c2 = MFMA16(Al[0], Bh[0], c2);
            f32x4 c0 = MFMA16(Ah[1], Bh[1], bp);
            f32x4 c3 = MFMA16(Al[1], Bh[1], ZERO4);
            c1 = MFMA16(Ah[2], Bh[2], c1);
            c2 = MFMA16(Al[2], Bh[2], c2);
            c0 = MFMA16(Ah[3], Bh[3], c0);
            c3 = MFMA16(Al[3], Bh[3], c3);
            f32x4 acc = (c0 + c1) + (c2 + c3);

            unsigned short o[4];
#pragma unroll
            for (int r = 0; r < 4; ++r) {
                float e = __expf(2.f * acc[r]);
                float hv = 1.f - 2.f * __builtin_amdgcn_rcpf(e + 1.f);
                o[r] = f16b((_Float16)hv);
            }
            uint2 pk; __builtin_memcpy(&pk, o, 8);
            const int G = (w * 2 + (q >> 1)) ^ (n & 7);
            *(uint2*)&hbuf[p ^ 1][n][G * 8 + (q & 1) * 4] = pk;  // critical publish
            hsbuf[tt] = pk;                                       // off-chain buffer

            if (tt == 15) {
                // flush hs chunk (16 b64 stores, vmcnt never waited in-loop)
#pragma unroll
                for (int k = 0; k < 16; ++k)
                    *(uint2*)(hsp + (size_t)(c16 * 16 + k) * (BATCH * HIDN)) = hsbuf[k];
                if (c16 < 15) write_chunk(cb ^ 1);
                if (c16 < 14) issue_chunk(c16 + 2);
            }

            asm volatile("" ::: "memory");
            __builtin_amdgcn_s_waitcnt(0xC07F);  // lgkmcnt(0) only
            __builtin_amdgcn_s_barrier();
            asm volatile("" ::: "memory");
            xB = xBn;
        }
    }
}

// Fused upsample(16->32, align_corners) + hardswish + mean + out-GEMM.
__global__ __launch_bounds__(256) void pool_out_kernel(
    const unsigned short* __restrict__ hs, const float* __restrict__ W_out,
    const float* __restrict__ b_out, float* __restrict__ out)
{
    const int b = blockIdx.x, tid = threadIdx.x;
    __shared__ unsigned short m[L][HIDN];   // 64 KB fp16
    __shared__ float ps[2][HIDN];
    __shared__ float pooled_s[HIDN];

#pragma unroll
    for (int it = 0; it < 16; ++it) {
        int i = tid + it * 256;
        int t = i >> 4, g = i & 15;
        *(uint4*)&m[t][g * 8] =
            *(const uint4*)(hs + (size_t)t * (BATCH * HIDN) + b * HIDN + g * 8);
    }
    __syncthreads();

    const int jo = tid & 127, sub = tid >> 7;
    float acc = 0.f;
    for (int oy = sub * 16; oy < sub * 16 + 16; ++oy) {
        float ysf = oy * (15.f / 31.f);
        int y0 = (int)ysf; float wy = ysf - (float)y0; int y1 = min(y0 + 1, 15);
        float rb[16];
#pragma unroll
        for (int sx = 0; sx < 16; ++sx) {
            float v0 = (float)*(const _Float16*)&m[y0 * 16 + sx][jo];
            float v1 = (float)*(const _Float16*)&m[y1 * 16 + sx][jo];
            rb[sx] = v0 + wy * (v1 - v0);
        }
#pragma unroll
        for (int ox = 0; ox < 32; ++ox) {
            float xsf = ox * (15.f / 31.f);
            int x0 = (int)xsf; float wx = xsf - (float)x0; int x1 = min(x0 + 1, 15);
            float v = rb[x0] + wx * (rb[x1] - rb[x0]);
            float t6 = fminf(fmaxf(v + 3.f, 0.f), 6.f);
            acc += v * t6;
        }
    }
    ps[sub][jo] = acc;
    __syncthreads();
    if (tid < 128) pooled_s[tid] = (ps[0][tid] + ps[1][tid]) * (1.f / 6144.f);
    __syncthreads();

    for (int o = tid; o < OUTN; o += 256) {
        float a = b_out[o];
#pragma unroll 8
        for (int k = 0; k < HIDN; k += 4) {
            float4 wv = *(const float4*)(W_out + o * HIDN + k);
            float4 pv = *(const float4*)&pooled_s[k];
            a += wv.x * pv.x + wv.y * pv.y + wv.z * pv.z + wv.w * pv.w;
        }
        out[b * OUTN + o] = a;
    }
}

extern "C" void kernel_launch(void* const* d_in, const int* in_sizes, int n_in,
                              void* d_out, int out_size, void* d_ws, size_t ws_size,
                              hipStream_t stream)
{
    const float* x     = (const float*)d_in[0];
    const float* h0    = (const float*)d_in[1];
    const float* W_in  = (const float*)d_in[2];
    const float* b_in  = (const float*)d_in[3];
    const float* W_ih  = (const float*)d_in[4];
    const float* b_ih  = (const float*)d_in[5];
    const float* W_hh  = (const float*)d_in[6];
    const float* b_hh  = (const float*)d_in[7];
    const float* W_out = (const float*)d_in[8];
    const float* b_out = (const float*)d_in[9];
    float* out = (float*)d_out;

    char* wsb = (char*)d_ws;
    unsigned short* Wh  = (unsigned short*)(wsb);
    unsigned short* Wl  = (unsigned short*)(wsb + 32768);
    unsigned short* Wch = (unsigned short*)(wsb + 65536);
    unsigned short* Wcl = (unsigned short*)(wsb + 73728);
    float* bpre         = (float*)(wsb + 81920);
    unsigned short* hsb = (unsigned short*)(wsb + 98304);

    prep_kernel<<<1, 256, 0, stream>>>(W_in, b_in, W_ih, b_ih, b_hh, W_hh,
                                       Wh, Wl, Wch, Wcl, bpre);
    rnn_kernel<<<32, 512, 0, stream>>>(x, h0, Wh, Wl, Wch, Wcl, bpre, hsb);
    pool_out_kernel<<<512, 256, 0, stream>>>(hsb, W_out, b_out, out);
}